// Round 13
// baseline (572.467 us; speedup 1.0000x reference)
//
#include <hip/hip_runtime.h>
#include <math.h>

typedef __attribute__((ext_vector_type(8))) short short8;
typedef __attribute__((ext_vector_type(8))) unsigned short u16x8;
typedef __attribute__((ext_vector_type(4))) float f32x4;
typedef unsigned short ushort_t;

// ---------------- workspace layout (float-slots, ~21.6 MB) ----------------
constexpr size_t OFF_HINT = 0;                                // 64*160
constexpr size_t OFF_HGRD = OFF_HINT + (size_t)64*160;        // 64*160
constexpr size_t OFF_F    = OFF_HGRD + (size_t)64*160;        // 64*4096
constexpr size_t OFF_H1   = OFF_F    + (size_t)64*4096;       // 64*256
constexpr size_t OFF_P5   = OFF_H1   + (size_t)64*256;        // 64*1024
constexpr size_t OFF_WHI  = OFF_P5   + (size_t)64*1024;       // 2,506,752 u16 = 1,253,376 slots
constexpr size_t W1_OFF = 0;         constexpr int K1T = 363,  K1R = 384;   // 64  x 384
constexpr size_t W2_OFF = 24576;     constexpr int K2T = 1600, K2R = 1664;  // 192 x 1664
constexpr size_t W3_OFF = 344064;    constexpr int K3T = 1728, K3R = 1792;  // 384 x 1792
constexpr size_t W4_OFF = 1032192;   constexpr int K4T = 3456, K4R = 3456;  // 256 x 3456
constexpr size_t W5_OFF = 1916928;   constexpr int K5T = 2304, K5R = 2304;  // 256 x 2304
constexpr size_t WP_U16 = 2506752;
constexpr size_t OFF_WLO  = OFF_WHI + WP_U16/2;
constexpr size_t OFF_RA   = OFF_WLO + WP_U16/2;               // 2,583,552 u16 (x0p / p1p / p2p+a4p)
constexpr size_t SZ_RA    = (size_t)2583552/2;
constexpr size_t A4P_U16  = 786432;                           // a4p offset within RA (u16 units)
constexpr size_t OFF_RB   = OFF_RA + SZ_RA;                   // 2,985,984 u16 (a1 / a2 / a3p / a5)
constexpr size_t SZ_RB    = (size_t)2985984/2;
constexpr size_t WS_FLOATS = OFF_RB + SZ_RB;                  // 5,656,064 slots

__device__ __forceinline__ void bf16split(float v, unsigned short& hi, unsigned short& lo) {
  union { float f; unsigned u; } a; a.f = v;
  unsigned uh = (a.u + 0x7FFFu + ((a.u >> 16) & 1u)) >> 16;
  hi = (unsigned short)uh;
  union { unsigned u; float f; } b; b.u = uh << 16;
  float rem = v - b.f;
  union { float f; unsigned u; } c; c.f = rem;
  lo = (unsigned short)((c.u + 0x7FFFu + ((c.u >> 16) & 1u)) >> 16);
}
__device__ __forceinline__ ushort_t f2bf(float f) {
  union { float f; unsigned u; } a; a.f = f;
  return (ushort_t)((a.u + 0x7FFFu + ((a.u >> 16) & 1u)) >> 16);
}
__device__ __forceinline__ float bf2f(ushort_t u) {
  union { unsigned u; float f; } a; a.u = ((unsigned)u) << 16; return a.f;
}

// ---------------- single-launch weight pre-split for all 5 layers ----------------
__global__ __launch_bounds__(256) void k_wsplit_all(const float* __restrict__ w1,
                                                    const float* __restrict__ w2,
                                                    const float* __restrict__ w3,
                                                    const float* __restrict__ w4,
                                                    const float* __restrict__ w5,
                                                    ushort_t* __restrict__ whi,
                                                    ushort_t* __restrict__ wlo) {
  const size_t idx = (size_t)blockIdx.x * 256 + threadIdx.x;
  if (idx >= WP_U16) return;
  const float* w; int kt, kr; size_t base;
  if (idx < W2_OFF)                { w = w1; kt = K1T; kr = K1R; base = W1_OFF; }
  else if (idx < W3_OFF)           { w = w2; kt = K2T; kr = K2R; base = W2_OFF; }
  else if (idx < W4_OFF)           { w = w3; kt = K3T; kr = K3R; base = W3_OFF; }
  else if (idx < W5_OFF)           { w = w4; kt = K4T; kr = K4R; base = W4_OFF; }
  else                             { w = w5; kt = K5T; kr = K5R; base = W5_OFF; }
  const size_t rel = idx - base;
  const int m = (int)(rel / kr), k = (int)(rel - (size_t)m * kr);
  const float v = (k < kt) ? w[(size_t)m * kt + k] : 0.f;
  unsigned short h, l;
  bf16split(v, h, l);
  whi[idx] = h; wlo[idx] = l;
}

// ---------------- fused preproc: two-pass hist (64-key u8 columns) + resize ----------------
__global__ __launch_bounds__(256) void k_preproc(const float* __restrict__ img,
                                                 float* __restrict__ hint,
                                                 float* __restrict__ hgrd,
                                                 ushort_t* __restrict__ x0) {
  const int b = blockIdx.x, s = blockIdx.y;     // 56 strips of 8 rows
  const int r0 = s * 8;
  __shared__ float gs[10][448];                 // 17920 B
  __shared__ unsigned char lh[64 * 260];        // 16640 B
  __shared__ ushort_t part[8 * 112 * 3];        // 5376 B
  const int tid = threadIdx.x;
  for (int i = tid; i < (64 * 260) / 4; i += 256) ((unsigned*)lh)[i] = 0u;
  const float* ib = img + (size_t)b * 4 * 200704;
  for (int i = tid; i < 10 * 112; i += 256) {
    const int rr = i / 112, cc = i % 112, c4 = cc * 4;
    int r = r0 + rr - 1; r = r < 0 ? 0 : (r > 447 ? 447 : r);
    const size_t o = (size_t)r * 448 + c4;
    const float4 vr = *(const float4*)&ib[o];
    const float4 g1 = *(const float4*)&ib[200704 + o];
    const float4 g2 = *(const float4*)&ib[2 * 200704 + o];
    const float4 vb = *(const float4*)&ib[3 * 200704 + o];
    float4 g;
    g.x = 0.299f * vr.x + 0.587f * (0.5f * (g1.x + g2.x)) + 0.114f * vb.x;
    g.y = 0.299f * vr.y + 0.587f * (0.5f * (g1.y + g2.y)) + 0.114f * vb.y;
    g.z = 0.299f * vr.z + 0.587f * (0.5f * (g1.z + g2.z)) + 0.114f * vb.z;
    g.w = 0.299f * vr.w + 0.587f * (0.5f * (g1.w + g2.w)) + 0.114f * vb.w;
    *(float4*)&gs[rr][c4] = g;
    if (rr >= 1 && rr <= 8) {
      const float sr = vr.x + vr.y + vr.z + vr.w;
      const float sg = 0.5f * (g1.x + g2.x) + 0.5f * (g1.y + g2.y)
                     + 0.5f * (g1.z + g2.z) + 0.5f * (g1.w + g2.w);
      const float sb = vb.x + vb.y + vb.z + vb.w;
      ushort_t* pp = &part[((rr - 1) * 112 + cc) * 3];
      pp[0] = f2bf(sr); pp[1] = f2bf(sg); pp[2] = f2bf(sb);
    }
  }
  __syncthreads();
  for (int i = tid; i < 672; i += 256) {
    const int cc = i % 112;
    const int t  = i / 112;
    const int or2 = t & 1, ch = t >> 1;
    float sum = 0.f;
    #pragma unroll
    for (int rw = 0; rw < 4; ++rw)
      sum += bf2f(part[((or2 * 4 + rw) * 112 + cc) * 3 + ch]);
    x0[(((size_t)b * 3 + ch) * 116 + 2 + 2 * s + or2) * 116 + 2 + cc] = f2bf(sum * (1.f / 16.f));
  }
  // pass 1: intensity hist
  for (int i = tid; i < 8 * 112; i += 256) {
    const int dr = i / 112, c4 = (i % 112) * 4;
    const unsigned colbit = (c4 >= 224) ? 1u : 0u;
    const float4 m1 = *(const float4*)&gs[dr + 1][c4];
    const float gv[4] = {m1.x, m1.y, m1.z, m1.w};
    #pragma unroll
    for (int j = 0; j < 4; ++j) {
      int bin = (int)(gv[j] * 32.f); bin = bin > 31 ? 31 : (bin < 0 ? 0 : bin);
      lh[(colbit * 32u + (unsigned)bin) * 260u + (unsigned)tid]++;
    }
  }
  __syncthreads();
  const unsigned rowbit = (s >= 28) ? 1u : 0u;
  {
    const int key = tid >> 2, quarter = tid & 3;
    const unsigned* row = (const unsigned*)&lh[(unsigned)key * 260u];
    unsigned sum = 0;
    #pragma unroll
    for (int d = 0; d < 16; ++d) {
      const unsigned v = row[quarter * 16 + d];
      sum += (v & 0xFFu) + ((v >> 8) & 0xFFu) + ((v >> 16) & 0xFFu) + (v >> 24);
    }
    sum += __shfl_down(sum, 1, 64);
    sum += __shfl_down(sum, 2, 64);
    if (quarter == 0) {
      const int colbit2 = key >> 5, bin = key & 31;
      atomicAdd(&hint[(size_t)b * 160 + 32 + (rowbit * 2 + colbit2) * 32 + bin], (float)sum);
    }
  }
  __syncthreads();
  for (int i = tid; i < (64 * 260) / 4; i += 256) ((unsigned*)lh)[i] = 0u;
  __syncthreads();
  // pass 2: sobel hist
  for (int i = tid; i < 8 * 112; i += 256) {
    const int dr = i / 112, c4 = (i % 112) * 4;
    const unsigned colbit = (c4 >= 224) ? 1u : 0u;
    const int cl = c4 > 0 ? c4 - 1 : 0;
    const int cr = c4 < 444 ? c4 + 4 : 447;
    const float4 m0 = *(const float4*)&gs[dr][c4];
    const float4 m1 = *(const float4*)&gs[dr + 1][c4];
    const float4 m2 = *(const float4*)&gs[dr + 2][c4];
    const float r0v[6] = {gs[dr][cl],     m0.x, m0.y, m0.z, m0.w, gs[dr][cr]};
    const float r1v[6] = {gs[dr + 1][cl], m1.x, m1.y, m1.z, m1.w, gs[dr + 1][cr]};
    const float r2v[6] = {gs[dr + 2][cl], m2.x, m2.y, m2.z, m2.w, gs[dr + 2][cr]};
    #pragma unroll
    for (int j = 0; j < 4; ++j) {
      const float gx = (-r0v[j] + r0v[j + 2] - 2.f * r1v[j] + 2.f * r1v[j + 2]
                        - r2v[j] + r2v[j + 2]) * 0.125f;
      const float gy = (-r0v[j] - 2.f * r0v[j + 1] - r0v[j + 2]
                        + r2v[j] + 2.f * r2v[j + 1] + r2v[j + 2]) * 0.125f;
      const float mag = sqrtf(gx * gx + gy * gy + 1e-6f);
      int sb = (int)(mag * 32.f); sb = sb > 31 ? 31 : (sb < 0 ? 0 : sb);
      lh[(colbit * 32u + (unsigned)sb) * 260u + (unsigned)tid]++;
    }
  }
  __syncthreads();
  {
    const int key = tid >> 2, quarter = tid & 3;
    const unsigned* row = (const unsigned*)&lh[(unsigned)key * 260u];
    unsigned sum = 0;
    #pragma unroll
    for (int d = 0; d < 16; ++d) {
      const unsigned v = row[quarter * 16 + d];
      sum += (v & 0xFFu) + ((v >> 8) & 0xFFu) + ((v >> 16) & 0xFFu) + (v >> 24);
    }
    sum += __shfl_down(sum, 1, 64);
    sum += __shfl_down(sum, 2, 64);
    if (quarter == 0) {
      const int colbit2 = key >> 5, bin = key & 31;
      atomicAdd(&hgrd[(size_t)b * 160 + 32 + (rowbit * 2 + colbit2) * 32 + bin], (float)sum);
    }
  }
}

// ---------------- conv MFMA v3: wave = 32 rows x (32|16) cols -> 4 MFMAs per ds_read ----------------
// 512 threads = 2 K-split groups x 4 waves. B double-buffered in LDS (reg-prefetch),
// A read directly from L2-hot global hi/lo weight rows inside the compute phase.
template<int CIN, int HP, int WP, int KH, int KW, int STRIDE, int OH, int OW,
         int OHP, int OWP, int OPAD, int M, int MT>
__global__ __launch_bounds__(512) void k_conv_mfma(const ushort_t* __restrict__ in,
                                                   const ushort_t* __restrict__ whi_,
                                                   const ushort_t* __restrict__ wlo_,
                                                   const float* __restrict__ bias,
                                                   ushort_t* __restrict__ out) {
  constexpr int K_TOT  = CIN * KH * KW;
  constexpr int K_ROUND = ((K_TOT + 127) / 128) * 128;
  constexpr int GSTEPS = K_ROUND / 128;
  constexpr int KHW = KH * KW;
  constexpr int NPB = OH * OW;
  constexpr int NF = (MT == 64) ? 2 : 1;    // n-frags per wave
  __shared__ ushort_t Bs[2][2][64 * 64];    // [K-group][dbuf], 32 KB
  __shared__ ushort_t ftab[K_ROUND];
  const int tid = threadIdx.x;
  const int lane = tid & 63, wv = tid >> 6;
  const int g = wv >> 2, wg = wv & 3;
  const int sub = tid & 255;
  const int n0 = blockIdx.x * 64, m0 = blockIdx.y * MT;
  for (int k = tid; k < K_ROUND; k += 512) {
    const int c = k / KHW, kr = k - c * KHW;
    const int ky = kr / KW, kx = kr - (kr / KW) * KW;
    ftab[k] = (k < K_TOT) ? (ushort_t)(2 * ((c * HP + ky) * WP + kx)) : (ushort_t)0;
  }
  // B staging coords (unchanged)
  const int col = sub & 63, kc2 = sub >> 6;
  const int nb = n0 + col;
  const int bB = nb / NPB, rB = nb % NPB;
  const int oyB = rB / OW, oxB = rB % OW;
  const char* baseB = (const char*)(in + (size_t)bB * CIN * HP * WP)
                      + 2 * (oyB * STRIDE * WP + oxB * STRIDE);
  // compute coords: wave owns rows [mbaseL, +32), cols [nbaseL, +16*NF)
  const int wm = (MT == 64) ? (wg & 1) : 0;
  const int wn = (MT == 64) ? (wg >> 1) : wg;
  const int mbaseL = wm * 32;
  const int nbaseL = (MT == 64) ? wn * 32 : wn * 16;
  const int mrow0 = m0 + mbaseL + (lane & 15);
  const int mrow1 = mrow0 + 16;
  const ushort_t* wh0 = whi_ + (size_t)mrow0 * K_ROUND;
  const ushort_t* wl0 = wlo_ + (size_t)mrow0 * K_ROUND;
  const ushort_t* wh1 = whi_ + (size_t)mrow1 * K_ROUND;
  const ushort_t* wl1 = wlo_ + (size_t)mrow1 * K_ROUND;
  const int kA = (lane >> 4) * 8;
  f32x4 acc[2][2] = {};   // [mf][nf]
  const int kb0 = g * GSTEPS * 64;
  __syncthreads();   // ftab ready

  u16x8 rb0, rb1;    // B prefetch regs
  {
    const int kb = kb0;
    const u16x8 f0 = *(const u16x8*)&ftab[kb + kc2 * 16];
    const u16x8 f1 = *(const u16x8*)&ftab[kb + kc2 * 16 + 8];
    #pragma unroll
    for (int j = 0; j < 8; ++j) rb0[j] = *(const ushort_t*)(baseB + f0[j]);
    #pragma unroll
    for (int j = 0; j < 8; ++j) rb1[j] = *(const ushort_t*)(baseB + f1[j]);
  }
  {
    const int c0 = kc2 * 2, c1 = c0 + 1;
    *(u16x8*)&Bs[g][0][col * 64 + ((c0 ^ (col & 7)) * 8)] = rb0;
    *(u16x8*)&Bs[g][0][col * 64 + ((c1 ^ (col & 7)) * 8)] = rb1;
  }
  __syncthreads();
  int cur = 0;
  for (int step = 0; step < GSTEPS; ++step) {
    const int kb = kb0 + step * 64;
    if (step + 1 < GSTEPS) {   // prefetch next B into regs (overlaps MFMA below)
      const int kbn = kb + 64;
      const u16x8 f0 = *(const u16x8*)&ftab[kbn + kc2 * 16];
      const u16x8 f1 = *(const u16x8*)&ftab[kbn + kc2 * 16 + 8];
      #pragma unroll
      for (int j = 0; j < 8; ++j) rb0[j] = *(const ushort_t*)(baseB + f0[j]);
      #pragma unroll
      for (int j = 0; j < 8; ++j) rb1[j] = *(const ushort_t*)(baseB + f1[j]);
    }
    // MFMA phase on Bs[g][cur]: per s, 4 A-loads (L2) + NF ds_reads + 4*NF MFMAs
    #pragma unroll
    for (int s = 0; s < 2; ++s) {
      const int kk = kb + s * 32 + kA;
      const short8 ah0 = *(const short8*)&wh0[kk];
      const short8 al0 = *(const short8*)&wl0[kk];
      const short8 ah1 = *(const short8*)&wh1[kk];
      const short8 al1 = *(const short8*)&wl1[kk];
      const int cA = s * 4 + (lane >> 4);
      #pragma unroll
      for (int nf = 0; nf < NF; ++nf) {
        const int coln = nbaseL + nf * 16 + (lane & 15);
        const short8 b_v = *(const short8*)&Bs[g][cur][coln * 64 + ((cA ^ (coln & 7)) * 8)];
        acc[0][nf] = __builtin_amdgcn_mfma_f32_16x16x32_bf16(ah0, b_v, acc[0][nf], 0, 0, 0);
        acc[0][nf] = __builtin_amdgcn_mfma_f32_16x16x32_bf16(al0, b_v, acc[0][nf], 0, 0, 0);
        acc[1][nf] = __builtin_amdgcn_mfma_f32_16x16x32_bf16(ah1, b_v, acc[1][nf], 0, 0, 0);
        acc[1][nf] = __builtin_amdgcn_mfma_f32_16x16x32_bf16(al1, b_v, acc[1][nf], 0, 0, 0);
      }
    }
    if (step + 1 < GSTEPS) {
      const int c0 = kc2 * 2, c1 = c0 + 1;
      *(u16x8*)&Bs[g][cur ^ 1][col * 64 + ((c0 ^ (col & 7)) * 8)] = rb0;
      *(u16x8*)&Bs[g][cur ^ 1][col * 64 + ((c1 ^ (col & 7)) * 8)] = rb1;
      __syncthreads();
      cur ^= 1;
    }
  }
  __syncthreads();
  // cross-group reduce through LDS (scratch overlays Bs): MT*64 floats
  float* scratch = (float*)&Bs[0][0][0];
  if (g == 1) {
    #pragma unroll
    for (int mf = 0; mf < 2; ++mf)
      #pragma unroll
      for (int nf = 0; nf < NF; ++nf)
        #pragma unroll
        for (int q = 0; q < 4; ++q)
          scratch[(mbaseL + mf * 16 + (lane >> 4) * 4 + q) * 64
                  + nbaseL + nf * 16 + (lane & 15)] = acc[mf][nf][q];
  }
  __syncthreads();
  if (g == 0) {
    #pragma unroll
    for (int mf = 0; mf < 2; ++mf)
      #pragma unroll
      for (int q = 0; q < 4; ++q) {
        const int m = m0 + mbaseL + mf * 16 + (lane >> 4) * 4 + q;
        const float bi = bias[m];
        #pragma unroll
        for (int nf = 0; nf < NF; ++nf) {
          const int nl = nbaseL + nf * 16 + (lane & 15);
          const int n = n0 + nl;
          const float v = acc[mf][nf][q]
                        + scratch[(mbaseL + mf * 16 + (lane >> 4) * 4 + q) * 64 + nl]
                        + bi;
          const int b = n / NPB, r = n % NPB;
          const int oy = r / OW, ox = r - (r / OW) * OW;
          out[(((size_t)b * M + m) * OHP + OPAD + oy) * OWP + OPAD + ox] = f2bf(fmaxf(v, 0.f));
        }
      }
  }
}

// ---------------- maxpool 3x3 s2 on bf16 bits -> padded output with zero ring ----------------
template<int C, int HI, int HO, int HOP, int PAD, bool OUTF32>
__global__ __launch_bounds__(256) void k_pool(const ushort_t* __restrict__ in,
                                              void* __restrict__ out) {
  const int idx = blockIdx.x * 256 + threadIdx.x;
  constexpr int TOT = 64 * C * HOP * HOP;
  if (idx >= TOT) return;
  const int x = idx % HOP;
  const int y = (idx / HOP) % HOP;
  const int c = (idx / (HOP * HOP)) % C;
  const int b = idx / (HOP * HOP * C);
  ushort_t v = 0;
  const int oy = y - PAD, ox = x - PAD;
  if (oy >= 0 && oy < HO && ox >= 0 && ox < HO) {
    const ushort_t* ib = in + (size_t)(b * C + c) * HI * HI + (size_t)(oy * 2) * HI + ox * 2;
    #pragma unroll
    for (int i = 0; i < 3; ++i)
      #pragma unroll
      for (int j = 0; j < 3; ++j) {
        const ushort_t u = ib[i * HI + j];
        v = u > v ? u : v;
      }
  }
  if constexpr (OUTF32) ((float*)out)[idx] = bf2f(v);
  else                  ((ushort_t*)out)[idx] = v;
}

// ---------------- feature assembly (h0 reconstructed from quadrant sums) ----------------
__global__ __launch_bounds__(256) void k_feat(const float* __restrict__ p5,
                                              const float* __restrict__ hint,
                                              const float* __restrict__ hgrad,
                                              float* __restrict__ f) {
  const int b = blockIdx.x, tid = threadIdx.x;
  __shared__ float tmp4[4];
  __shared__ float vals[160];
  const float* ps = p5 + (size_t)b * 1024;
  float* fb = f + (size_t)b * 4096;
  float mv[4]; float ss = 0.f;
  #pragma unroll
  for (int i = 0; i < 4; ++i) { mv[i] = ps[tid + i * 256]; ss += mv[i] * mv[i]; }
  #pragma unroll
  for (int o = 32; o > 0; o >>= 1) ss += __shfl_down(ss, o, 64);
  if ((tid & 63) == 0) tmp4[tid >> 6] = ss;
  __syncthreads();
  const float inv = 1.f / (sqrtf(tmp4[0] + tmp4[1] + tmp4[2] + tmp4[3]) + 1e-7f);
  #pragma unroll
  for (int i = 0; i < 4; ++i) fb[tid + i * 256] = fmaxf(mv[i] * inv, 0.f);
  for (int ft = 0; ft < 2; ++ft) {
    const float* hb = (ft ? hgrad : hint) + (size_t)b * 160;
    __syncthreads();
    if (tid < 160) {
      float cnt;
      if (tid < 32) cnt = hb[32 + tid] + hb[64 + tid] + hb[96 + tid] + hb[128 + tid];
      else          cnt = hb[tid];
      vals[tid] = cnt * (tid < 32 ? (1.f / 200704.f) : (1.f / 50176.f));
    }
    __syncthreads();
    float s2 = 0.f;
    if (tid < 160) s2 = (tid < 32 ? 16.f : 4.f) * vals[tid] * vals[tid];
    #pragma unroll
    for (int o = 32; o > 0; o >>= 1) s2 += __shfl_down(s2, o, 64);
    __syncthreads();
    if ((tid & 63) == 0) tmp4[tid >> 6] = s2;
    __syncthreads();
    const float inv2 = 1.f / (sqrtf(tmp4[0] + tmp4[1] + tmp4[2] + tmp4[3]) + 1e-7f);
    float* fo = fb + 1024 + ft * 1536;
    for (int idx = tid; idx < 1536; idx += 256) {
      const int ch = idx >> 4, i2 = (idx >> 2) & 3, j = idx & 3;
      float v;
      if (ch < 32)      v = vals[ch];
      else if (ch < 64) v = vals[32 + (((i2 >> 1) * 2) + (j >> 1)) * 32 + (ch - 32)];
      else              v = 0.f;
      fo[idx] = fmaxf(v * inv2, 0.f);
    }
  }
}

// ---------------- fc1: one wave per (b,oc) ----------------
__global__ __launch_bounds__(256) void k_fc1(const float* __restrict__ f,
                                             const float* __restrict__ w,
                                             const float* __restrict__ bias,
                                             float* __restrict__ h1) {
  const int gid = blockIdx.x * 4 + (threadIdx.x >> 6);
  const int lane = threadIdx.x & 63;
  if (gid >= 64 * 256) return;
  const int oc = gid & 255, b = gid >> 8;
  const float* fb = f + (size_t)b * 4096;
  const float* wr = w + (size_t)oc * 4096;
  float s = 0.f;
  for (int k = lane; k < 4096; k += 64) s += fb[k] * wr[k];
  #pragma unroll
  for (int o = 32; o > 0; o >>= 1) s += __shfl_down(s, o, 64);
  if (lane == 0) h1[(size_t)b * 256 + oc] = fmaxf(s + bias[oc], 0.f);
}

// ---------------- fc2 ----------------
__global__ __launch_bounds__(256) void k_fc2_simple(const float* __restrict__ h1,
                                                    const float* __restrict__ w,
                                                    const float* __restrict__ bias,
                                                    float* __restrict__ out) {
  const int idx = blockIdx.x * 256 + threadIdx.x;
  if (idx >= 64 * 12) return;
  const int oc = idx % 12, b = idx / 12;
  const float* hb = h1 + (size_t)b * 256;
  const float* wr = w + (size_t)oc * 256;
  float s = bias[oc];
  for (int k = 0; k < 256; ++k) s += hb[k] * wr[k];
  out[b * 12 + oc] = s;
}

// ---------------- launch ----------------
extern "C" void kernel_launch(void* const* d_in, const int* in_sizes, int n_in,
                              void* d_out, int out_size, void* d_ws, size_t ws_size,
                              hipStream_t stream) {
  const float* img  = (const float*)d_in[0];
  const float* w1 = (const float*)d_in[1];  const float* b1 = (const float*)d_in[2];
  const float* w2 = (const float*)d_in[3];  const float* b2 = (const float*)d_in[4];
  const float* w3 = (const float*)d_in[5];  const float* b3 = (const float*)d_in[6];
  const float* w4 = (const float*)d_in[7];  const float* b4 = (const float*)d_in[8];
  const float* w5 = (const float*)d_in[9];  const float* b5 = (const float*)d_in[10];
  const float* fc1w = (const float*)d_in[11]; const float* fc1b = (const float*)d_in[12];
  const float* fc2w = (const float*)d_in[13]; const float* fc2b = (const float*)d_in[14];
  float* out = (float*)d_out;
  float* ws  = (float*)d_ws;

  float* hint = ws + OFF_HINT;
  float* hgrd = ws + OFF_HGRD;
  float* f    = ws + OFF_F;
  float* h1   = ws + OFF_H1;
  float* p5   = ws + OFF_P5;
  ushort_t* whi = (ushort_t*)(ws + OFF_WHI);
  ushort_t* wlo = (ushort_t*)(ws + OFF_WLO);
  ushort_t* ra  = (ushort_t*)(ws + OFF_RA);   // x0p / p1p / p2p ; a4p at +A4P_U16
  ushort_t* rb  = (ushort_t*)(ws + OFF_RB);   // a1 / a2 / a3p / a5

  hipMemsetAsync(hint, 0, (size_t)2 * 64 * 160 * sizeof(float), stream);
  hipMemsetAsync(ra, 0, (size_t)64 * 3 * 116 * 116 * 2, stream);   // x0p incl. zero ring

  k_wsplit_all<<<(int)((WP_U16 + 255) / 256), 256, 0, stream>>>(w1, w2, w3, w4, w5, whi, wlo);

  // fused hist + resize (single pass over the 205 MB image)
  k_preproc<<<dim3(64, 56), 256, 0, stream>>>(img, hint, hgrd, ra);

  // conv1: [b][3][116][116] -> a1 [b][64][27][27] (RB)
  k_conv_mfma<3,116,116,11,11,4,27,27,27,27,0,64,64>
      <<<dim3(729, 1), 512, 0, stream>>>(ra, whi + W1_OFF, wlo + W1_OFF, b1, rb);
  // pool1 -> p1p [b][64][17][17] pad2 (RA)
  k_pool<64,27,13,17,2,false><<<(64*64*17*17 + 255)/256, 256, 0, stream>>>(rb, ra);
  // conv2: -> a2 [b][192][13][13] (RB)
  k_conv_mfma<64,17,17,5,5,1,13,13,13,13,0,192,64>
      <<<dim3(169, 3), 512, 0, stream>>>(ra, whi + W2_OFF, wlo + W2_OFF, b2, rb);
  // pool2 -> p2p [b][192][8][8] pad1 (RA)
  k_pool<192,13,6,8,1,false><<<(64*192*8*8 + 255)/256, 256, 0, stream>>>(rb, ra);
  // zero pad rings for conv3/conv4 padded outputs
  hipMemsetAsync(rb, 0, (size_t)64*384*8*8*2, stream);                      // a3p
  hipMemsetAsync(ra + A4P_U16, 0, (size_t)64*256*8*8*2, stream);            // a4p
  // conv3: p2p -> a3p [b][384][8][8] pad1 interior (RB)
  k_conv_mfma<192,8,8,3,3,1,6,6,8,8,1,384,32>
      <<<dim3(36, 12), 512, 0, stream>>>(ra, whi + W3_OFF, wlo + W3_OFF, b3, rb);
  // conv4: a3p -> a4p [b][256][8][8] pad1 interior (RA + A4P_U16)
  k_conv_mfma<384,8,8,3,3,1,6,6,8,8,1,256,32>
      <<<dim3(36, 8), 512, 0, stream>>>(rb, whi + W4_OFF, wlo + W4_OFF, b4, ra + A4P_U16);
  // conv5: a4p -> a5 [b][256][6][6] (RB)
  k_conv_mfma<256,8,8,3,3,1,6,6,6,6,0,256,32>
      <<<dim3(36, 8), 512, 0, stream>>>(ra + A4P_U16, whi + W5_OFF, wlo + W5_OFF, b5, rb);
  // pool5 -> p5 f32 [b][256][2][2]
  k_pool<256,6,2,2,0,true><<<(64*256*2*2 + 255)/256, 256, 0, stream>>>(rb, p5);

  k_feat<<<64, 256, 0, stream>>>(p5, hint, hgrd, f);
  k_fc1<<<(64*256)/4, 256, 0, stream>>>(f, fc1w, fc1b, h1);
  k_fc2_simple<<<(64*12 + 255)/256, 256, 0, stream>>>(h1, fc2w, fc2b, out);
}

// Round 14
// 448.950 us; speedup vs baseline: 1.2751x; 1.2751x over previous
//
#include <hip/hip_runtime.h>
#include <math.h>

typedef __attribute__((ext_vector_type(8))) short short8;
typedef __attribute__((ext_vector_type(8))) unsigned short u16x8;
typedef __attribute__((ext_vector_type(4))) float f32x4;
typedef unsigned short ushort_t;

// ---------------- workspace layout (float-slots, ~21.6 MB) ----------------
constexpr size_t OFF_HINT = 0;                                // 64*160
constexpr size_t OFF_HGRD = OFF_HINT + (size_t)64*160;        // 64*160
constexpr size_t OFF_F    = OFF_HGRD + (size_t)64*160;        // 64*4096
constexpr size_t OFF_H1   = OFF_F    + (size_t)64*4096;       // 64*256
constexpr size_t OFF_P5   = OFF_H1   + (size_t)64*256;        // 64*1024
constexpr size_t OFF_WHI  = OFF_P5   + (size_t)64*1024;       // 2,506,752 u16 = 1,253,376 slots
constexpr size_t W1_OFF = 0;         constexpr int K1T = 363,  K1R = 384;   // 64  x 384
constexpr size_t W2_OFF = 24576;     constexpr int K2T = 1600, K2R = 1664;  // 192 x 1664
constexpr size_t W3_OFF = 344064;    constexpr int K3T = 1728, K3R = 1792;  // 384 x 1792
constexpr size_t W4_OFF = 1032192;   constexpr int K4T = 3456, K4R = 3456;  // 256 x 3456
constexpr size_t W5_OFF = 1916928;   constexpr int K5T = 2304, K5R = 2304;  // 256 x 2304
constexpr size_t WP_U16 = 2506752;
constexpr size_t OFF_WLO  = OFF_WHI + WP_U16/2;
constexpr size_t OFF_RA   = OFF_WLO + WP_U16/2;               // 2,583,552 u16 (x0p / p1p / p2p+a4p)
constexpr size_t SZ_RA    = (size_t)2583552/2;
constexpr size_t A4P_U16  = 786432;                           // a4p offset within RA (u16 units)
constexpr size_t OFF_RB   = OFF_RA + SZ_RA;                   // 2,985,984 u16 (a1 / a2 / a3p / a5)
constexpr size_t SZ_RB    = (size_t)2985984/2;
constexpr size_t WS_FLOATS = OFF_RB + SZ_RB;                  // 5,656,064 slots

__device__ __forceinline__ void bf16split(float v, unsigned short& hi, unsigned short& lo) {
  union { float f; unsigned u; } a; a.f = v;
  unsigned uh = (a.u + 0x7FFFu + ((a.u >> 16) & 1u)) >> 16;
  hi = (unsigned short)uh;
  union { unsigned u; float f; } b; b.u = uh << 16;
  float rem = v - b.f;
  union { float f; unsigned u; } c; c.f = rem;
  lo = (unsigned short)((c.u + 0x7FFFu + ((c.u >> 16) & 1u)) >> 16);
}
__device__ __forceinline__ ushort_t f2bf(float f) {
  union { float f; unsigned u; } a; a.f = f;
  return (ushort_t)((a.u + 0x7FFFu + ((a.u >> 16) & 1u)) >> 16);
}
__device__ __forceinline__ float bf2f(ushort_t u) {
  union { unsigned u; float f; } a; a.u = ((unsigned)u) << 16; return a.f;
}

// ---------------- single-launch weight pre-split for all 5 layers ----------------
__global__ __launch_bounds__(256) void k_wsplit_all(const float* __restrict__ w1,
                                                    const float* __restrict__ w2,
                                                    const float* __restrict__ w3,
                                                    const float* __restrict__ w4,
                                                    const float* __restrict__ w5,
                                                    ushort_t* __restrict__ whi,
                                                    ushort_t* __restrict__ wlo) {
  const size_t idx = (size_t)blockIdx.x * 256 + threadIdx.x;
  if (idx >= WP_U16) return;
  const float* w; int kt, kr; size_t base;
  if (idx < W2_OFF)                { w = w1; kt = K1T; kr = K1R; base = W1_OFF; }
  else if (idx < W3_OFF)           { w = w2; kt = K2T; kr = K2R; base = W2_OFF; }
  else if (idx < W4_OFF)           { w = w3; kt = K3T; kr = K3R; base = W3_OFF; }
  else if (idx < W5_OFF)           { w = w4; kt = K4T; kr = K4R; base = W4_OFF; }
  else                             { w = w5; kt = K5T; kr = K5R; base = W5_OFF; }
  const size_t rel = idx - base;
  const int m = (int)(rel / kr), k = (int)(rel - (size_t)m * kr);
  const float v = (k < kt) ? w[(size_t)m * kt + k] : 0.f;
  unsigned short h, l;
  bf16split(v, h, l);
  whi[idx] = h; wlo[idx] = l;
}

// ---------------- fused preproc: two-pass hist (64-key u8 columns) + resize ----------------
__global__ __launch_bounds__(256) void k_preproc(const float* __restrict__ img,
                                                 float* __restrict__ hint,
                                                 float* __restrict__ hgrd,
                                                 ushort_t* __restrict__ x0) {
  const int b = blockIdx.x, s = blockIdx.y;     // 56 strips of 8 rows
  const int r0 = s * 8;
  __shared__ float gs[10][448];                 // 17920 B
  __shared__ unsigned char lh[64 * 260];        // 16640 B
  __shared__ ushort_t part[8 * 112 * 3];        // 5376 B
  const int tid = threadIdx.x;
  for (int i = tid; i < (64 * 260) / 4; i += 256) ((unsigned*)lh)[i] = 0u;
  const float* ib = img + (size_t)b * 4 * 200704;
  for (int i = tid; i < 10 * 112; i += 256) {
    const int rr = i / 112, cc = i % 112, c4 = cc * 4;
    int r = r0 + rr - 1; r = r < 0 ? 0 : (r > 447 ? 447 : r);
    const size_t o = (size_t)r * 448 + c4;
    const float4 vr = *(const float4*)&ib[o];
    const float4 g1 = *(const float4*)&ib[200704 + o];
    const float4 g2 = *(const float4*)&ib[2 * 200704 + o];
    const float4 vb = *(const float4*)&ib[3 * 200704 + o];
    float4 g;
    g.x = 0.299f * vr.x + 0.587f * (0.5f * (g1.x + g2.x)) + 0.114f * vb.x;
    g.y = 0.299f * vr.y + 0.587f * (0.5f * (g1.y + g2.y)) + 0.114f * vb.y;
    g.z = 0.299f * vr.z + 0.587f * (0.5f * (g1.z + g2.z)) + 0.114f * vb.z;
    g.w = 0.299f * vr.w + 0.587f * (0.5f * (g1.w + g2.w)) + 0.114f * vb.w;
    *(float4*)&gs[rr][c4] = g;
    if (rr >= 1 && rr <= 8) {
      const float sr = vr.x + vr.y + vr.z + vr.w;
      const float sg = 0.5f * (g1.x + g2.x) + 0.5f * (g1.y + g2.y)
                     + 0.5f * (g1.z + g2.z) + 0.5f * (g1.w + g2.w);
      const float sb = vb.x + vb.y + vb.z + vb.w;
      ushort_t* pp = &part[((rr - 1) * 112 + cc) * 3];
      pp[0] = f2bf(sr); pp[1] = f2bf(sg); pp[2] = f2bf(sb);
    }
  }
  __syncthreads();
  for (int i = tid; i < 672; i += 256) {
    const int cc = i % 112;
    const int t  = i / 112;
    const int or2 = t & 1, ch = t >> 1;
    float sum = 0.f;
    #pragma unroll
    for (int rw = 0; rw < 4; ++rw)
      sum += bf2f(part[((or2 * 4 + rw) * 112 + cc) * 3 + ch]);
    x0[(((size_t)b * 3 + ch) * 116 + 2 + 2 * s + or2) * 116 + 2 + cc] = f2bf(sum * (1.f / 16.f));
  }
  // pass 1: intensity hist
  for (int i = tid; i < 8 * 112; i += 256) {
    const int dr = i / 112, c4 = (i % 112) * 4;
    const unsigned colbit = (c4 >= 224) ? 1u : 0u;
    const float4 m1 = *(const float4*)&gs[dr + 1][c4];
    const float gv[4] = {m1.x, m1.y, m1.z, m1.w};
    #pragma unroll
    for (int j = 0; j < 4; ++j) {
      int bin = (int)(gv[j] * 32.f); bin = bin > 31 ? 31 : (bin < 0 ? 0 : bin);
      lh[(colbit * 32u + (unsigned)bin) * 260u + (unsigned)tid]++;
    }
  }
  __syncthreads();
  const unsigned rowbit = (s >= 28) ? 1u : 0u;
  {
    const int key = tid >> 2, quarter = tid & 3;
    const unsigned* row = (const unsigned*)&lh[(unsigned)key * 260u];
    unsigned sum = 0;
    #pragma unroll
    for (int d = 0; d < 16; ++d) {
      const unsigned v = row[quarter * 16 + d];
      sum += (v & 0xFFu) + ((v >> 8) & 0xFFu) + ((v >> 16) & 0xFFu) + (v >> 24);
    }
    sum += __shfl_down(sum, 1, 64);
    sum += __shfl_down(sum, 2, 64);
    if (quarter == 0) {
      const int colbit2 = key >> 5, bin = key & 31;
      atomicAdd(&hint[(size_t)b * 160 + 32 + (rowbit * 2 + colbit2) * 32 + bin], (float)sum);
    }
  }
  __syncthreads();
  for (int i = tid; i < (64 * 260) / 4; i += 256) ((unsigned*)lh)[i] = 0u;
  __syncthreads();
  // pass 2: sobel hist
  for (int i = tid; i < 8 * 112; i += 256) {
    const int dr = i / 112, c4 = (i % 112) * 4;
    const unsigned colbit = (c4 >= 224) ? 1u : 0u;
    const int cl = c4 > 0 ? c4 - 1 : 0;
    const int cr = c4 < 444 ? c4 + 4 : 447;
    const float4 m0 = *(const float4*)&gs[dr][c4];
    const float4 m1 = *(const float4*)&gs[dr + 1][c4];
    const float4 m2 = *(const float4*)&gs[dr + 2][c4];
    const float r0v[6] = {gs[dr][cl],     m0.x, m0.y, m0.z, m0.w, gs[dr][cr]};
    const float r1v[6] = {gs[dr + 1][cl], m1.x, m1.y, m1.z, m1.w, gs[dr + 1][cr]};
    const float r2v[6] = {gs[dr + 2][cl], m2.x, m2.y, m2.z, m2.w, gs[dr + 2][cr]};
    #pragma unroll
    for (int j = 0; j < 4; ++j) {
      const float gx = (-r0v[j] + r0v[j + 2] - 2.f * r1v[j] + 2.f * r1v[j + 2]
                        - r2v[j] + r2v[j + 2]) * 0.125f;
      const float gy = (-r0v[j] - 2.f * r0v[j + 1] - r0v[j + 2]
                        + r2v[j] + 2.f * r2v[j + 1] + r2v[j + 2]) * 0.125f;
      const float mag = sqrtf(gx * gx + gy * gy + 1e-6f);
      int sb = (int)(mag * 32.f); sb = sb > 31 ? 31 : (sb < 0 ? 0 : sb);
      lh[(colbit * 32u + (unsigned)sb) * 260u + (unsigned)tid]++;
    }
  }
  __syncthreads();
  {
    const int key = tid >> 2, quarter = tid & 3;
    const unsigned* row = (const unsigned*)&lh[(unsigned)key * 260u];
    unsigned sum = 0;
    #pragma unroll
    for (int d = 0; d < 16; ++d) {
      const unsigned v = row[quarter * 16 + d];
      sum += (v & 0xFFu) + ((v >> 8) & 0xFFu) + ((v >> 16) & 0xFFu) + (v >> 24);
    }
    sum += __shfl_down(sum, 1, 64);
    sum += __shfl_down(sum, 2, 64);
    if (quarter == 0) {
      const int colbit2 = key >> 5, bin = key & 31;
      atomicAdd(&hgrd[(size_t)b * 160 + 32 + (rowbit * 2 + colbit2) * 32 + bin], (float)sum);
    }
  }
}

// ---------------- conv MFMA (r12 version, reverted): dbuf LDS + reg prefetch A+B ----------------
template<int CIN, int HP, int WP, int KH, int KW, int STRIDE, int OH, int OW,
         int OHP, int OWP, int OPAD, int M, int MT>
__global__ __launch_bounds__(512) void k_conv_mfma(const ushort_t* __restrict__ in,
                                                   const ushort_t* __restrict__ whi_,
                                                   const ushort_t* __restrict__ wlo_,
                                                   const float* __restrict__ bias,
                                                   ushort_t* __restrict__ out) {
  constexpr int K_TOT  = CIN * KH * KW;
  constexpr int K_ROUND = ((K_TOT + 127) / 128) * 128;
  constexpr int GSTEPS = K_ROUND / 128;
  constexpr int KHW = KH * KW;
  constexpr int NPB = OH * OW;
  constexpr int WROWS = MT / 16;
  constexpr int TGRP  = 4 / WROWS;
  constexpr int TFRAG = 4 / TGRP;
  __shared__ ushort_t Bs[2][2][64 * 64];   // [K-group][dbuf][..], 32 KB
  __shared__ ushort_t ftab[K_ROUND];
  const int tid = threadIdx.x;
  const int lane = tid & 63, wv = tid >> 6;
  const int g = wv >> 2, wg = wv & 3;
  const int sub = tid & 255;
  const int n0 = blockIdx.x * 64, m0 = blockIdx.y * MT;
  for (int k = tid; k < K_ROUND; k += 512) {
    const int c = k / KHW, kr = k - c * KHW;
    const int ky = kr / KW, kx = kr - (kr / KW) * KW;
    ftab[k] = (k < K_TOT) ? (ushort_t)(2 * ((c * HP + ky) * WP + kx)) : (ushort_t)0;
  }
  const int col = sub & 63, kc2 = sub >> 6;
  const int nb = n0 + col;
  const int bB = nb / NPB, rB = nb % NPB;
  const int oyB = rB / OW, oxB = rB % OW;
  const char* baseB = (const char*)(in + (size_t)bB * CIN * HP * WP)
                      + 2 * (oyB * STRIDE * WP + oxB * STRIDE);
  const int wm = wg % WROWS, tg = wg / WROWS;
  const int mrow = m0 + wm * 16 + (lane & 15);
  const ushort_t* wh = whi_ + (size_t)mrow * K_ROUND;
  const ushort_t* wl = wlo_ + (size_t)mrow * K_ROUND;
  const int kA = (lane >> 4) * 8;
  f32x4 acc[TFRAG] = {};
  const int kb0 = g * GSTEPS * 64;
  __syncthreads();   // ftab ready

  u16x8 rb0, rb1;                     // B prefetch regs
  short8 rah0, ral0, rah1, ral1;      // A prefetch regs (sub-steps 0,1)
  {
    const int kb = kb0;
    const u16x8 f0 = *(const u16x8*)&ftab[kb + kc2 * 16];
    const u16x8 f1 = *(const u16x8*)&ftab[kb + kc2 * 16 + 8];
    #pragma unroll
    for (int j = 0; j < 8; ++j) rb0[j] = *(const ushort_t*)(baseB + f0[j]);
    #pragma unroll
    for (int j = 0; j < 8; ++j) rb1[j] = *(const ushort_t*)(baseB + f1[j]);
    rah0 = *(const short8*)&wh[kb + kA];
    ral0 = *(const short8*)&wl[kb + kA];
    rah1 = *(const short8*)&wh[kb + 32 + kA];
    ral1 = *(const short8*)&wl[kb + 32 + kA];
  }
  {
    const int c0 = kc2 * 2, c1 = c0 + 1;
    *(u16x8*)&Bs[g][0][col * 64 + ((c0 ^ (col & 7)) * 8)] = rb0;
    *(u16x8*)&Bs[g][0][col * 64 + ((c1 ^ (col & 7)) * 8)] = rb1;
  }
  __syncthreads();
  int cur = 0;
  for (int step = 0; step < GSTEPS; ++step) {
    const short8 a_h0 = rah0, a_l0 = ral0, a_h1 = rah1, a_l1 = ral1;
    if (step + 1 < GSTEPS) {
      const int kb = kb0 + (step + 1) * 64;
      const u16x8 f0 = *(const u16x8*)&ftab[kb + kc2 * 16];
      const u16x8 f1 = *(const u16x8*)&ftab[kb + kc2 * 16 + 8];
      #pragma unroll
      for (int j = 0; j < 8; ++j) rb0[j] = *(const ushort_t*)(baseB + f0[j]);
      #pragma unroll
      for (int j = 0; j < 8; ++j) rb1[j] = *(const ushort_t*)(baseB + f1[j]);
      rah0 = *(const short8*)&wh[kb + kA];
      ral0 = *(const short8*)&wl[kb + kA];
      rah1 = *(const short8*)&wh[kb + 32 + kA];
      ral1 = *(const short8*)&wl[kb + 32 + kA];
    }
    #pragma unroll
    for (int s = 0; s < 2; ++s) {
      const short8 a_h = s ? a_h1 : a_h0;
      const short8 a_l = s ? a_l1 : a_l0;
      const int cA = s * 4 + (lane >> 4);
      #pragma unroll
      for (int tt = 0; tt < TFRAG; ++tt) {
        const int t = tg * TFRAG + tt;
        const int coln = t * 16 + (lane & 15);
        const short8 b_v = *(const short8*)&Bs[g][cur][coln * 64 + ((cA ^ (coln & 7)) * 8)];
        acc[tt] = __builtin_amdgcn_mfma_f32_16x16x32_bf16(a_h, b_v, acc[tt], 0, 0, 0);
        acc[tt] = __builtin_amdgcn_mfma_f32_16x16x32_bf16(a_l, b_v, acc[tt], 0, 0, 0);
      }
    }
    if (step + 1 < GSTEPS) {
      const int c0 = kc2 * 2, c1 = c0 + 1;
      *(u16x8*)&Bs[g][cur ^ 1][col * 64 + ((c0 ^ (col & 7)) * 8)] = rb0;
      *(u16x8*)&Bs[g][cur ^ 1][col * 64 + ((c1 ^ (col & 7)) * 8)] = rb1;
      __syncthreads();
      cur ^= 1;
    }
  }
  __syncthreads();
  float* scratch = (float*)&Bs[0][0][0];
  if (g == 1) {
    #pragma unroll
    for (int tt = 0; tt < TFRAG; ++tt) {
      const int t = tg * TFRAG + tt;
      #pragma unroll
      for (int q = 0; q < 4; ++q)
        scratch[(wm * 16 + (lane >> 4) * 4 + q) * 64 + t * 16 + (lane & 15)] = acc[tt][q];
    }
  }
  __syncthreads();
  if (g == 0) {
    #pragma unroll
    for (int q = 0; q < 4; ++q) {
      const int m = m0 + wm * 16 + (lane >> 4) * 4 + q;
      const float bi = bias[m];
      #pragma unroll
      for (int tt = 0; tt < TFRAG; ++tt) {
        const int t = tg * TFRAG + tt;
        const int n = n0 + t * 16 + (lane & 15);
        const float v = acc[tt][q]
                      + scratch[(wm * 16 + (lane >> 4) * 4 + q) * 64 + t * 16 + (lane & 15)]
                      + bi;
        const int b = n / NPB, r = n % NPB;
        const int oy = r / OW, ox = r - (r / OW) * OW;
        out[(((size_t)b * M + m) * OHP + OPAD + oy) * OWP + OPAD + ox] = f2bf(fmaxf(v, 0.f));
      }
    }
  }
}

// ---------------- maxpool 3x3 s2 on bf16 bits -> padded output with zero ring ----------------
template<int C, int HI, int HO, int HOP, int PAD, bool OUTF32>
__global__ __launch_bounds__(256) void k_pool(const ushort_t* __restrict__ in,
                                              void* __restrict__ out) {
  const int idx = blockIdx.x * 256 + threadIdx.x;
  constexpr int TOT = 64 * C * HOP * HOP;
  if (idx >= TOT) return;
  const int x = idx % HOP;
  const int y = (idx / HOP) % HOP;
  const int c = (idx / (HOP * HOP)) % C;
  const int b = idx / (HOP * HOP * C);
  ushort_t v = 0;
  const int oy = y - PAD, ox = x - PAD;
  if (oy >= 0 && oy < HO && ox >= 0 && ox < HO) {
    const ushort_t* ib = in + (size_t)(b * C + c) * HI * HI + (size_t)(oy * 2) * HI + ox * 2;
    #pragma unroll
    for (int i = 0; i < 3; ++i)
      #pragma unroll
      for (int j = 0; j < 3; ++j) {
        const ushort_t u = ib[i * HI + j];
        v = u > v ? u : v;
      }
  }
  if constexpr (OUTF32) ((float*)out)[idx] = bf2f(v);
  else                  ((ushort_t*)out)[idx] = v;
}

// ---------------- feature assembly (h0 reconstructed from quadrant sums) ----------------
__global__ __launch_bounds__(256) void k_feat(const float* __restrict__ p5,
                                              const float* __restrict__ hint,
                                              const float* __restrict__ hgrad,
                                              float* __restrict__ f) {
  const int b = blockIdx.x, tid = threadIdx.x;
  __shared__ float tmp4[4];
  __shared__ float vals[160];
  const float* ps = p5 + (size_t)b * 1024;
  float* fb = f + (size_t)b * 4096;
  float mv[4]; float ss = 0.f;
  #pragma unroll
  for (int i = 0; i < 4; ++i) { mv[i] = ps[tid + i * 256]; ss += mv[i] * mv[i]; }
  #pragma unroll
  for (int o = 32; o > 0; o >>= 1) ss += __shfl_down(ss, o, 64);
  if ((tid & 63) == 0) tmp4[tid >> 6] = ss;
  __syncthreads();
  const float inv = 1.f / (sqrtf(tmp4[0] + tmp4[1] + tmp4[2] + tmp4[3]) + 1e-7f);
  #pragma unroll
  for (int i = 0; i < 4; ++i) fb[tid + i * 256] = fmaxf(mv[i] * inv, 0.f);
  for (int ft = 0; ft < 2; ++ft) {
    const float* hb = (ft ? hgrad : hint) + (size_t)b * 160;
    __syncthreads();
    if (tid < 160) {
      float cnt;
      if (tid < 32) cnt = hb[32 + tid] + hb[64 + tid] + hb[96 + tid] + hb[128 + tid];
      else          cnt = hb[tid];
      vals[tid] = cnt * (tid < 32 ? (1.f / 200704.f) : (1.f / 50176.f));
    }
    __syncthreads();
    float s2 = 0.f;
    if (tid < 160) s2 = (tid < 32 ? 16.f : 4.f) * vals[tid] * vals[tid];
    #pragma unroll
    for (int o = 32; o > 0; o >>= 1) s2 += __shfl_down(s2, o, 64);
    __syncthreads();
    if ((tid & 63) == 0) tmp4[tid >> 6] = s2;
    __syncthreads();
    const float inv2 = 1.f / (sqrtf(tmp4[0] + tmp4[1] + tmp4[2] + tmp4[3]) + 1e-7f);
    float* fo = fb + 1024 + ft * 1536;
    for (int idx = tid; idx < 1536; idx += 256) {
      const int ch = idx >> 4, i2 = (idx >> 2) & 3, j = idx & 3;
      float v;
      if (ch < 32)      v = vals[ch];
      else if (ch < 64) v = vals[32 + (((i2 >> 1) * 2) + (j >> 1)) * 32 + (ch - 32)];
      else              v = 0.f;
      fo[idx] = fmaxf(v * inv2, 0.f);
    }
  }
}

// ---------------- fc1 v2: one wave = (1 oc x 8 batches) -> 8x less weight traffic ----------------
__global__ __launch_bounds__(256) void k_fc1(const float* __restrict__ f,
                                             const float* __restrict__ w,
                                             const float* __restrict__ bias,
                                             float* __restrict__ h1) {
  const int gid = blockIdx.x * 4 + (threadIdx.x >> 6);   // 2048 waves
  const int lane = threadIdx.x & 63;
  if (gid >= 256 * 8) return;
  const int oc = gid >> 3, bg = gid & 7;                 // oc, batch-group of 8
  const float* wr = w + (size_t)oc * 4096;
  const float* fb = f + (size_t)(bg * 8) * 4096;
  float s[8] = {};
  for (int k = lane; k < 4096; k += 64) {
    const float wv = wr[k];
    #pragma unroll
    for (int i = 0; i < 8; ++i) s[i] += wv * fb[(size_t)i * 4096 + k];
  }
  #pragma unroll
  for (int i = 0; i < 8; ++i) {
    #pragma unroll
    for (int o = 32; o > 0; o >>= 1) s[i] += __shfl_down(s[i], o, 64);
  }
  if (lane == 0) {
    const float bi = bias[oc];
    #pragma unroll
    for (int i = 0; i < 8; ++i)
      h1[(size_t)(bg * 8 + i) * 256 + oc] = fmaxf(s[i] + bi, 0.f);
  }
}

// ---------------- fc2 ----------------
__global__ __launch_bounds__(256) void k_fc2_simple(const float* __restrict__ h1,
                                                    const float* __restrict__ w,
                                                    const float* __restrict__ bias,
                                                    float* __restrict__ out) {
  const int idx = blockIdx.x * 256 + threadIdx.x;
  if (idx >= 64 * 12) return;
  const int oc = idx % 12, b = idx / 12;
  const float* hb = h1 + (size_t)b * 256;
  const float* wr = w + (size_t)oc * 256;
  float s = bias[oc];
  for (int k = 0; k < 256; ++k) s += hb[k] * wr[k];
  out[b * 12 + oc] = s;
}

// ---------------- launch ----------------
extern "C" void kernel_launch(void* const* d_in, const int* in_sizes, int n_in,
                              void* d_out, int out_size, void* d_ws, size_t ws_size,
                              hipStream_t stream) {
  const float* img  = (const float*)d_in[0];
  const float* w1 = (const float*)d_in[1];  const float* b1 = (const float*)d_in[2];
  const float* w2 = (const float*)d_in[3];  const float* b2 = (const float*)d_in[4];
  const float* w3 = (const float*)d_in[5];  const float* b3 = (const float*)d_in[6];
  const float* w4 = (const float*)d_in[7];  const float* b4 = (const float*)d_in[8];
  const float* w5 = (const float*)d_in[9];  const float* b5 = (const float*)d_in[10];
  const float* fc1w = (const float*)d_in[11]; const float* fc1b = (const float*)d_in[12];
  const float* fc2w = (const float*)d_in[13]; const float* fc2b = (const float*)d_in[14];
  float* out = (float*)d_out;
  float* ws  = (float*)d_ws;

  float* hint = ws + OFF_HINT;
  float* hgrd = ws + OFF_HGRD;
  float* f    = ws + OFF_F;
  float* h1   = ws + OFF_H1;
  float* p5   = ws + OFF_P5;
  ushort_t* whi = (ushort_t*)(ws + OFF_WHI);
  ushort_t* wlo = (ushort_t*)(ws + OFF_WLO);
  ushort_t* ra  = (ushort_t*)(ws + OFF_RA);   // x0p / p1p / p2p ; a4p at +A4P_U16
  ushort_t* rb  = (ushort_t*)(ws + OFF_RB);   // a1 / a2 / a3p / a5

  hipMemsetAsync(hint, 0, (size_t)2 * 64 * 160 * sizeof(float), stream);
  hipMemsetAsync(ra, 0, (size_t)64 * 3 * 116 * 116 * 2, stream);   // x0p incl. zero ring

  k_wsplit_all<<<(int)((WP_U16 + 255) / 256), 256, 0, stream>>>(w1, w2, w3, w4, w5, whi, wlo);

  // fused hist + resize (single pass over the 205 MB image)
  k_preproc<<<dim3(64, 56), 256, 0, stream>>>(img, hint, hgrd, ra);

  // conv1: [b][3][116][116] -> a1 [b][64][27][27] (RB)
  k_conv_mfma<3,116,116,11,11,4,27,27,27,27,0,64,64>
      <<<dim3(729, 1), 512, 0, stream>>>(ra, whi + W1_OFF, wlo + W1_OFF, b1, rb);
  // pool1 -> p1p [b][64][17][17] pad2 (RA)
  k_pool<64,27,13,17,2,false><<<(64*64*17*17 + 255)/256, 256, 0, stream>>>(rb, ra);
  // conv2: -> a2 [b][192][13][13] (RB)
  k_conv_mfma<64,17,17,5,5,1,13,13,13,13,0,192,64>
      <<<dim3(169, 3), 512, 0, stream>>>(ra, whi + W2_OFF, wlo + W2_OFF, b2, rb);
  // pool2 -> p2p [b][192][8][8] pad1 (RA)
  k_pool<192,13,6,8,1,false><<<(64*192*8*8 + 255)/256, 256, 0, stream>>>(rb, ra);
  // zero pad rings for conv3/conv4 padded outputs
  hipMemsetAsync(rb, 0, (size_t)64*384*8*8*2, stream);                      // a3p
  hipMemsetAsync(ra + A4P_U16, 0, (size_t)64*256*8*8*2, stream);            // a4p
  // conv3: p2p -> a3p [b][384][8][8] pad1 interior (RB)
  k_conv_mfma<192,8,8,3,3,1,6,6,8,8,1,384,32>
      <<<dim3(36, 12), 512, 0, stream>>>(ra, whi + W3_OFF, wlo + W3_OFF, b3, rb);
  // conv4: a3p -> a4p [b][256][8][8] pad1 interior (RA + A4P_U16)
  k_conv_mfma<384,8,8,3,3,1,6,6,8,8,1,256,32>
      <<<dim3(36, 8), 512, 0, stream>>>(rb, whi + W4_OFF, wlo + W4_OFF, b4, ra + A4P_U16);
  // conv5: a4p -> a5 [b][256][6][6] (RB)
  k_conv_mfma<256,8,8,3,3,1,6,6,6,6,0,256,32>
      <<<dim3(36, 8), 512, 0, stream>>>(ra + A4P_U16, whi + W5_OFF, wlo + W5_OFF, b5, rb);
  // pool5 -> p5 f32 [b][256][2][2]
  k_pool<256,6,2,2,0,true><<<(64*256*2*2 + 255)/256, 256, 0, stream>>>(rb, p5);

  k_feat<<<64, 256, 0, stream>>>(p5, hint, hgrd, f);
  k_fc1<<<(256*8)/4, 256, 0, stream>>>(f, fc1w, fc1b, h1);
  k_fc2_simple<<<(64*12 + 255)/256, 256, 0, stream>>>(h1, fc2w, fc2b, out);
}

// Round 15
// 374.363 us; speedup vs baseline: 1.5292x; 1.1992x over previous
//
#include <hip/hip_runtime.h>
#include <math.h>

typedef __attribute__((ext_vector_type(8))) short short8;
typedef __attribute__((ext_vector_type(8))) unsigned short u16x8;
typedef __attribute__((ext_vector_type(4))) unsigned short u16x4;
typedef __attribute__((ext_vector_type(4))) float f32x4;
typedef unsigned short ushort_t;

// ---------------- workspace layout (float-slots, ~21.6 MB) ----------------
constexpr size_t OFF_HINT = 0;                                // 64*160
constexpr size_t OFF_HGRD = OFF_HINT + (size_t)64*160;        // 64*160
constexpr size_t OFF_F    = OFF_HGRD + (size_t)64*160;        // 64*4096
constexpr size_t OFF_H1   = OFF_F    + (size_t)64*4096;       // 64*256
constexpr size_t OFF_P5   = OFF_H1   + (size_t)64*256;        // 64*1024
constexpr size_t OFF_WHI  = OFF_P5   + (size_t)64*1024;       // 2,506,752 u16 = 1,253,376 slots
constexpr size_t W1_OFF = 0;         constexpr int K1T = 363,  K1R = 384;   // 64  x 384
constexpr size_t W2_OFF = 24576;     constexpr int K2T = 1600, K2R = 1664;  // 192 x 1664
constexpr size_t W3_OFF = 344064;    constexpr int K3T = 1728, K3R = 1792;  // 384 x 1792
constexpr size_t W4_OFF = 1032192;   constexpr int K4T = 3456, K4R = 3456;  // 256 x 3456
constexpr size_t W5_OFF = 1916928;   constexpr int K5T = 2304, K5R = 2304;  // 256 x 2304
constexpr size_t WP_U16 = 2506752;
constexpr size_t OFF_WLO  = OFF_WHI + WP_U16/2;
constexpr size_t OFF_RA   = OFF_WLO + WP_U16/2;               // 2,583,552 u16 (x0p / p1p / p2p+a4p)
constexpr size_t SZ_RA    = (size_t)2583552/2;
constexpr size_t A4P_U16  = 786432;                           // a4p offset within RA (u16 units)
constexpr size_t OFF_RB   = OFF_RA + SZ_RA;                   // 2,985,984 u16 (a1 / a2 / a3p / a5)
constexpr size_t SZ_RB    = (size_t)2985984/2;
constexpr size_t WS_FLOATS = OFF_RB + SZ_RB;                  // 5,656,064 slots

__device__ __forceinline__ void bf16split(float v, unsigned short& hi, unsigned short& lo) {
  union { float f; unsigned u; } a; a.f = v;
  unsigned uh = (a.u + 0x7FFFu + ((a.u >> 16) & 1u)) >> 16;
  hi = (unsigned short)uh;
  union { unsigned u; float f; } b; b.u = uh << 16;
  float rem = v - b.f;
  union { float f; unsigned u; } c; c.f = rem;
  lo = (unsigned short)((c.u + 0x7FFFu + ((c.u >> 16) & 1u)) >> 16);
}
__device__ __forceinline__ ushort_t f2bf(float f) {
  union { float f; unsigned u; } a; a.f = f;
  return (ushort_t)((a.u + 0x7FFFu + ((a.u >> 16) & 1u)) >> 16);
}
__device__ __forceinline__ float bf2f(ushort_t u) {
  union { unsigned u; float f; } a; a.u = ((unsigned)u) << 16; return a.f;
}

// ---------------- weight pre-split + reorder to k=(ky,kx,c) c-innermost ----------------
__global__ __launch_bounds__(256) void k_wsplit_all(const float* __restrict__ w1,
                                                    const float* __restrict__ w2,
                                                    const float* __restrict__ w3,
                                                    const float* __restrict__ w4,
                                                    const float* __restrict__ w5,
                                                    ushort_t* __restrict__ whi,
                                                    ushort_t* __restrict__ wlo) {
  const size_t idx = (size_t)blockIdx.x * 256 + threadIdx.x;
  if (idx >= WP_U16) return;
  const float* w; int cin, khw, kt, kr; size_t base;
  if (idx < W2_OFF)      { w = w1; cin = 3;   khw = 121; kt = K1T; kr = K1R; base = W1_OFF; }
  else if (idx < W3_OFF) { w = w2; cin = 64;  khw = 25;  kt = K2T; kr = K2R; base = W2_OFF; }
  else if (idx < W4_OFF) { w = w3; cin = 192; khw = 9;   kt = K3T; kr = K3R; base = W3_OFF; }
  else if (idx < W5_OFF) { w = w4; cin = 384; khw = 9;   kt = K4T; kr = K4R; base = W4_OFF; }
  else                   { w = w5; cin = 256; khw = 9;   kt = K5T; kr = K5R; base = W5_OFF; }
  const size_t rel = idx - base;
  const int m = (int)(rel / kr), k = (int)(rel - (size_t)m * kr);
  float v = 0.f;
  if (k < kt) {
    const int kyx = k / cin, c = k - kyx * cin;     // new order: (ky,kx) major, c minor
    v = w[(size_t)m * kt + c * khw + kyx];          // src NCHW: [m][c][ky][kx]
  }
  unsigned short h, l;
  bf16split(v, h, l);
  whi[idx] = h; wlo[idx] = l;
}

// ---------------- fused preproc: two-pass hist (u8 columns) + resize -> NHWC x0p ----------------
__global__ __launch_bounds__(256) void k_preproc(const float* __restrict__ img,
                                                 float* __restrict__ hint,
                                                 float* __restrict__ hgrd,
                                                 ushort_t* __restrict__ x0) {
  const int b = blockIdx.x, s = blockIdx.y;     // 56 strips of 8 rows
  const int r0 = s * 8;
  __shared__ float gs[10][448];                 // 17920 B
  __shared__ unsigned char lh[64 * 260];        // 16640 B
  __shared__ ushort_t part[8 * 112 * 3];        // 5376 B
  const int tid = threadIdx.x;
  for (int i = tid; i < (64 * 260) / 4; i += 256) ((unsigned*)lh)[i] = 0u;
  const float* ib = img + (size_t)b * 4 * 200704;
  for (int i = tid; i < 10 * 112; i += 256) {
    const int rr = i / 112, cc = i % 112, c4 = cc * 4;
    int r = r0 + rr - 1; r = r < 0 ? 0 : (r > 447 ? 447 : r);
    const size_t o = (size_t)r * 448 + c4;
    const float4 vr = *(const float4*)&ib[o];
    const float4 g1 = *(const float4*)&ib[200704 + o];
    const float4 g2 = *(const float4*)&ib[2 * 200704 + o];
    const float4 vb = *(const float4*)&ib[3 * 200704 + o];
    float4 g;
    g.x = 0.299f * vr.x + 0.587f * (0.5f * (g1.x + g2.x)) + 0.114f * vb.x;
    g.y = 0.299f * vr.y + 0.587f * (0.5f * (g1.y + g2.y)) + 0.114f * vb.y;
    g.z = 0.299f * vr.z + 0.587f * (0.5f * (g1.z + g2.z)) + 0.114f * vb.z;
    g.w = 0.299f * vr.w + 0.587f * (0.5f * (g1.w + g2.w)) + 0.114f * vb.w;
    *(float4*)&gs[rr][c4] = g;
    if (rr >= 1 && rr <= 8) {
      const float sr = vr.x + vr.y + vr.z + vr.w;
      const float sg = 0.5f * (g1.x + g2.x) + 0.5f * (g1.y + g2.y)
                     + 0.5f * (g1.z + g2.z) + 0.5f * (g1.w + g2.w);
      const float sb = vb.x + vb.y + vb.z + vb.w;
      ushort_t* pp = &part[((rr - 1) * 112 + cc) * 3];
      pp[0] = f2bf(sr); pp[1] = f2bf(sg); pp[2] = f2bf(sb);
    }
  }
  __syncthreads();
  // resize write -> NHWC [b][116][116][3], interior at +2
  for (int i = tid; i < 672; i += 256) {
    const int cc = i % 112;
    const int t  = i / 112;
    const int or2 = t & 1, ch = t >> 1;
    float sum = 0.f;
    #pragma unroll
    for (int rw = 0; rw < 4; ++rw)
      sum += bf2f(part[((or2 * 4 + rw) * 112 + cc) * 3 + ch]);
    x0[(((size_t)b * 116 + (2 + 2 * s + or2)) * 116 + (2 + cc)) * 3 + ch]
        = f2bf(sum * (1.f / 16.f));
  }
  // pass 1: intensity hist
  for (int i = tid; i < 8 * 112; i += 256) {
    const int dr = i / 112, c4 = (i % 112) * 4;
    const unsigned colbit = (c4 >= 224) ? 1u : 0u;
    const float4 m1 = *(const float4*)&gs[dr + 1][c4];
    const float gv[4] = {m1.x, m1.y, m1.z, m1.w};
    #pragma unroll
    for (int j = 0; j < 4; ++j) {
      int bin = (int)(gv[j] * 32.f); bin = bin > 31 ? 31 : (bin < 0 ? 0 : bin);
      lh[(colbit * 32u + (unsigned)bin) * 260u + (unsigned)tid]++;
    }
  }
  __syncthreads();
  const unsigned rowbit = (s >= 28) ? 1u : 0u;
  {
    const int key = tid >> 2, quarter = tid & 3;
    const unsigned* row = (const unsigned*)&lh[(unsigned)key * 260u];
    unsigned sum = 0;
    #pragma unroll
    for (int d = 0; d < 16; ++d) {
      const unsigned v = row[quarter * 16 + d];
      sum += (v & 0xFFu) + ((v >> 8) & 0xFFu) + ((v >> 16) & 0xFFu) + (v >> 24);
    }
    sum += __shfl_down(sum, 1, 64);
    sum += __shfl_down(sum, 2, 64);
    if (quarter == 0) {
      const int colbit2 = key >> 5, bin = key & 31;
      atomicAdd(&hint[(size_t)b * 160 + 32 + (rowbit * 2 + colbit2) * 32 + bin], (float)sum);
    }
  }
  __syncthreads();
  for (int i = tid; i < (64 * 260) / 4; i += 256) ((unsigned*)lh)[i] = 0u;
  __syncthreads();
  // pass 2: sobel hist
  for (int i = tid; i < 8 * 112; i += 256) {
    const int dr = i / 112, c4 = (i % 112) * 4;
    const unsigned colbit = (c4 >= 224) ? 1u : 0u;
    const int cl = c4 > 0 ? c4 - 1 : 0;
    const int cr = c4 < 444 ? c4 + 4 : 447;
    const float4 m0 = *(const float4*)&gs[dr][c4];
    const float4 m1 = *(const float4*)&gs[dr + 1][c4];
    const float4 m2 = *(const float4*)&gs[dr + 2][c4];
    const float r0v[6] = {gs[dr][cl],     m0.x, m0.y, m0.z, m0.w, gs[dr][cr]};
    const float r1v[6] = {gs[dr + 1][cl], m1.x, m1.y, m1.z, m1.w, gs[dr + 1][cr]};
    const float r2v[6] = {gs[dr + 2][cl], m2.x, m2.y, m2.z, m2.w, gs[dr + 2][cr]};
    #pragma unroll
    for (int j = 0; j < 4; ++j) {
      const float gx = (-r0v[j] + r0v[j + 2] - 2.f * r1v[j] + 2.f * r1v[j + 2]
                        - r2v[j] + r2v[j + 2]) * 0.125f;
      const float gy = (-r0v[j] - 2.f * r0v[j + 1] - r0v[j + 2]
                        + r2v[j] + 2.f * r2v[j + 1] + r2v[j + 2]) * 0.125f;
      const float mag = sqrtf(gx * gx + gy * gy + 1e-6f);
      int sb = (int)(mag * 32.f); sb = sb > 31 ? 31 : (sb < 0 ? 0 : sb);
      lh[(colbit * 32u + (unsigned)sb) * 260u + (unsigned)tid]++;
    }
  }
  __syncthreads();
  {
    const int key = tid >> 2, quarter = tid & 3;
    const unsigned* row = (const unsigned*)&lh[(unsigned)key * 260u];
    unsigned sum = 0;
    #pragma unroll
    for (int d = 0; d < 16; ++d) {
      const unsigned v = row[quarter * 16 + d];
      sum += (v & 0xFFu) + ((v >> 8) & 0xFFu) + ((v >> 16) & 0xFFu) + (v >> 24);
    }
    sum += __shfl_down(sum, 1, 64);
    sum += __shfl_down(sum, 2, 64);
    if (quarter == 0) {
      const int colbit2 = key >> 5, bin = key & 31;
      atomicAdd(&hgrd[(size_t)b * 160 + 32 + (rowbit * 2 + colbit2) * 32 + bin], (float)sum);
    }
  }
}

// ---------------- conv MFMA (NHWC): vector B staging for CIN%16==0, dbuf + reg prefetch ----------------
// in: [b][HP][WP][CIN] bf16 (zero pad ring); weights: hi/lo rows, k=(ky,kx,c) c-innermost;
// out: [b][OHP][OWP][M] bf16, interior at OPAD, relu+bias fused.
template<int CIN, int HP, int WP, int KH, int KW, int STRIDE, int OH, int OW,
         int OHP, int OWP, int OPAD, int M, int MT>
__global__ __launch_bounds__(512) void k_conv_mfma(const ushort_t* __restrict__ in,
                                                   const ushort_t* __restrict__ whi_,
                                                   const ushort_t* __restrict__ wlo_,
                                                   const float* __restrict__ bias,
                                                   ushort_t* __restrict__ out) {
  constexpr int K_TOT  = CIN * KH * KW;
  constexpr int K_ROUND = ((K_TOT + 127) / 128) * 128;
  constexpr int GSTEPS = K_ROUND / 128;
  constexpr int NPB = OH * OW;
  constexpr int WROWS = MT / 16;
  constexpr int TGRP  = 4 / WROWS;
  constexpr int TFRAG = 4 / TGRP;
  __shared__ ushort_t Bs[2][2][64 * 64];   // [K-group][dbuf], 32 KB
  __shared__ ushort_t ftab[K_ROUND];
  const int tid = threadIdx.x;
  const int lane = tid & 63, wv = tid >> 6;
  const int g = wv >> 2, wg = wv & 3;
  const int sub = tid & 255;
  const int n0 = blockIdx.x * 64, m0 = blockIdx.y * MT;
  for (int k = tid; k < K_ROUND; k += 512) {
    const int kyx = k / CIN, c = k - kyx * CIN;
    const int ky = kyx / KW, kx = kyx - (kyx / KW) * KW;
    ftab[k] = (k < K_TOT) ? (ushort_t)(2 * ((ky * WP + kx) * CIN + c)) : (ushort_t)0;
  }
  const int col = sub & 63, kc2 = sub >> 6;
  const int nb = n0 + col;
  const int bB = nb / NPB, rB = nb % NPB;
  const int oyB = rB / OW, oxB = rB % OW;
  const char* baseB = (const char*)(in + (size_t)bB * HP * WP * CIN)
                      + 2 * (size_t)(oyB * STRIDE * WP + oxB * STRIDE) * CIN;
  const int wm = wg % WROWS, tg = wg / WROWS;
  const int mrow = m0 + wm * 16 + (lane & 15);
  const ushort_t* wh = whi_ + (size_t)mrow * K_ROUND;
  const ushort_t* wl = wlo_ + (size_t)mrow * K_ROUND;
  const int kA = (lane >> 4) * 8;
  f32x4 acc[TFRAG] = {};
  const int kb0 = g * GSTEPS * 64;
  __syncthreads();   // ftab ready

  u16x8 rb0, rb1;                     // B prefetch regs
  short8 rah0, ral0, rah1, ral1;      // A prefetch regs
  auto loadB = [&](int kb) {
    if constexpr (CIN % 16 == 0) {
      // c-innermost: 16 consecutive k = 32 contiguous bytes
      const char* p = baseB + ftab[kb + kc2 * 16];
      rb0 = *(const u16x8*)(p);
      rb1 = *(const u16x8*)(p + 16);
    } else {
      const u16x8 f0 = *(const u16x8*)&ftab[kb + kc2 * 16];
      const u16x8 f1 = *(const u16x8*)&ftab[kb + kc2 * 16 + 8];
      #pragma unroll
      for (int j = 0; j < 8; ++j) rb0[j] = *(const ushort_t*)(baseB + f0[j]);
      #pragma unroll
      for (int j = 0; j < 8; ++j) rb1[j] = *(const ushort_t*)(baseB + f1[j]);
    }
  };
  {
    const int kb = kb0;
    loadB(kb);
    rah0 = *(const short8*)&wh[kb + kA];
    ral0 = *(const short8*)&wl[kb + kA];
    rah1 = *(const short8*)&wh[kb + 32 + kA];
    ral1 = *(const short8*)&wl[kb + 32 + kA];
  }
  {
    const int c0 = kc2 * 2, c1 = c0 + 1;
    *(u16x8*)&Bs[g][0][col * 64 + ((c0 ^ (col & 7)) * 8)] = rb0;
    *(u16x8*)&Bs[g][0][col * 64 + ((c1 ^ (col & 7)) * 8)] = rb1;
  }
  __syncthreads();
  int cur = 0;
  for (int step = 0; step < GSTEPS; ++step) {
    const short8 a_h0 = rah0, a_l0 = ral0, a_h1 = rah1, a_l1 = ral1;
    if (step + 1 < GSTEPS) {
      const int kb = kb0 + (step + 1) * 64;
      loadB(kb);
      rah0 = *(const short8*)&wh[kb + kA];
      ral0 = *(const short8*)&wl[kb + kA];
      rah1 = *(const short8*)&wh[kb + 32 + kA];
      ral1 = *(const short8*)&wl[kb + 32 + kA];
    }
    #pragma unroll
    for (int s = 0; s < 2; ++s) {
      const short8 a_h = s ? a_h1 : a_h0;
      const short8 a_l = s ? a_l1 : a_l0;
      const int cA = s * 4 + (lane >> 4);
      #pragma unroll
      for (int tt = 0; tt < TFRAG; ++tt) {
        const int t = tg * TFRAG + tt;
        const int coln = t * 16 + (lane & 15);
        const short8 b_v = *(const short8*)&Bs[g][cur][coln * 64 + ((cA ^ (coln & 7)) * 8)];
        acc[tt] = __builtin_amdgcn_mfma_f32_16x16x32_bf16(a_h, b_v, acc[tt], 0, 0, 0);
        acc[tt] = __builtin_amdgcn_mfma_f32_16x16x32_bf16(a_l, b_v, acc[tt], 0, 0, 0);
      }
    }
    if (step + 1 < GSTEPS) {
      const int c0 = kc2 * 2, c1 = c0 + 1;
      *(u16x8*)&Bs[g][cur ^ 1][col * 64 + ((c0 ^ (col & 7)) * 8)] = rb0;
      *(u16x8*)&Bs[g][cur ^ 1][col * 64 + ((c1 ^ (col & 7)) * 8)] = rb1;
      __syncthreads();
      cur ^= 1;
    }
  }
  __syncthreads();
  float* scratch = (float*)&Bs[0][0][0];
  if (g == 1) {
    #pragma unroll
    for (int tt = 0; tt < TFRAG; ++tt) {
      const int t = tg * TFRAG + tt;
      #pragma unroll
      for (int q = 0; q < 4; ++q)
        scratch[(wm * 16 + (lane >> 4) * 4 + q) * 64 + t * 16 + (lane & 15)] = acc[tt][q];
    }
  }
  __syncthreads();
  if (g == 0) {
    const int mb = m0 + wm * 16 + (lane >> 4) * 4;
    #pragma unroll
    for (int tt = 0; tt < TFRAG; ++tt) {
      const int t = tg * TFRAG + tt;
      const int nl = t * 16 + (lane & 15);
      const int n = n0 + nl;
      const int b = n / NPB, r = n % NPB;
      const int oy = r / OW, ox = r - (r / OW) * OW;
      u16x4 pk;
      #pragma unroll
      for (int q = 0; q < 4; ++q) {
        const float v = acc[tt][q]
                      + scratch[(wm * 16 + (lane >> 4) * 4 + q) * 64 + nl]
                      + bias[mb + q];
        pk[q] = f2bf(fmaxf(v, 0.f));
      }
      *(u16x4*)&out[(((size_t)b * OHP + OPAD + oy) * OWP + (OPAD + ox)) * M + mb] = pk;
    }
  }
}

// ---------------- maxpool 3x3 s2, NHWC in -> NHWC padded out (or NCHW f32 for pool5) ----------------
template<int C, int HI, int HO, int HOP, int PAD, bool OUTF32>
__global__ __launch_bounds__(256) void k_pool(const ushort_t* __restrict__ in,
                                              void* __restrict__ out) {
  const int idx = blockIdx.x * 256 + threadIdx.x;
  constexpr int TOT = 64 * C * HOP * HOP;
  if (idx >= TOT) return;
  const int c = idx % C;
  const int x = (idx / C) % HOP;
  const int y = (idx / (C * HOP)) % HOP;
  const int b = idx / (C * HOP * HOP);
  ushort_t v = 0;
  const int oy = y - PAD, ox = x - PAD;
  if (oy >= 0 && oy < HO && ox >= 0 && ox < HO) {
    const ushort_t* ib = in + (((size_t)b * HI + oy * 2) * HI + ox * 2) * C + c;
    #pragma unroll
    for (int i = 0; i < 3; ++i)
      #pragma unroll
      for (int j = 0; j < 3; ++j) {
        const ushort_t u = ib[(i * HI + j) * C];
        v = u > v ? u : v;
      }
  }
  if constexpr (OUTF32)   // pool5: transpose to NCHW f32 for k_feat
    ((float*)out)[((size_t)b * C + c) * (HO * HO) + y * HO + x] = bf2f(v);
  else
    ((ushort_t*)out)[idx] = v;
}

// ---------------- feature assembly (h0 reconstructed from quadrant sums) ----------------
__global__ __launch_bounds__(256) void k_feat(const float* __restrict__ p5,
                                              const float* __restrict__ hint,
                                              const float* __restrict__ hgrad,
                                              float* __restrict__ f) {
  const int b = blockIdx.x, tid = threadIdx.x;
  __shared__ float tmp4[4];
  __shared__ float vals[160];
  const float* ps = p5 + (size_t)b * 1024;
  float* fb = f + (size_t)b * 4096;
  float mv[4]; float ss = 0.f;
  #pragma unroll
  for (int i = 0; i < 4; ++i) { mv[i] = ps[tid + i * 256]; ss += mv[i] * mv[i]; }
  #pragma unroll
  for (int o = 32; o > 0; o >>= 1) ss += __shfl_down(ss, o, 64);
  if ((tid & 63) == 0) tmp4[tid >> 6] = ss;
  __syncthreads();
  const float inv = 1.f / (sqrtf(tmp4[0] + tmp4[1] + tmp4[2] + tmp4[3]) + 1e-7f);
  #pragma unroll
  for (int i = 0; i < 4; ++i) fb[tid + i * 256] = fmaxf(mv[i] * inv, 0.f);
  for (int ft = 0; ft < 2; ++ft) {
    const float* hb = (ft ? hgrad : hint) + (size_t)b * 160;
    __syncthreads();
    if (tid < 160) {
      float cnt;
      if (tid < 32) cnt = hb[32 + tid] + hb[64 + tid] + hb[96 + tid] + hb[128 + tid];
      else          cnt = hb[tid];
      vals[tid] = cnt * (tid < 32 ? (1.f / 200704.f) : (1.f / 50176.f));
    }
    __syncthreads();
    float s2 = 0.f;
    if (tid < 160) s2 = (tid < 32 ? 16.f : 4.f) * vals[tid] * vals[tid];
    #pragma unroll
    for (int o = 32; o > 0; o >>= 1) s2 += __shfl_down(s2, o, 64);
    __syncthreads();
    if ((tid & 63) == 0) tmp4[tid >> 6] = s2;
    __syncthreads();
    const float inv2 = 1.f / (sqrtf(tmp4[0] + tmp4[1] + tmp4[2] + tmp4[3]) + 1e-7f);
    float* fo = fb + 1024 + ft * 1536;
    for (int idx = tid; idx < 1536; idx += 256) {
      const int ch = idx >> 4, i2 = (idx >> 2) & 3, j = idx & 3;
      float v;
      if (ch < 32)      v = vals[ch];
      else if (ch < 64) v = vals[32 + (((i2 >> 1) * 2) + (j >> 1)) * 32 + (ch - 32)];
      else              v = 0.f;
      fo[idx] = fmaxf(v * inv2, 0.f);
    }
  }
}

// ---------------- fc1: one wave = (1 oc x 8 batches) ----------------
__global__ __launch_bounds__(256) void k_fc1(const float* __restrict__ f,
                                             const float* __restrict__ w,
                                             const float* __restrict__ bias,
                                             float* __restrict__ h1) {
  const int gid = blockIdx.x * 4 + (threadIdx.x >> 6);
  const int lane = threadIdx.x & 63;
  if (gid >= 256 * 8) return;
  const int oc = gid >> 3, bg = gid & 7;
  const float* wr = w + (size_t)oc * 4096;
  const float* fb = f + (size_t)(bg * 8) * 4096;
  float s[8] = {};
  for (int k = lane; k < 4096; k += 64) {
    const float wv = wr[k];
    #pragma unroll
    for (int i = 0; i < 8; ++i) s[i] += wv * fb[(size_t)i * 4096 + k];
  }
  #pragma unroll
  for (int i = 0; i < 8; ++i) {
    #pragma unroll
    for (int o = 32; o > 0; o >>= 1) s[i] += __shfl_down(s[i], o, 64);
  }
  if (lane == 0) {
    const float bi = bias[oc];
    #pragma unroll
    for (int i = 0; i < 8; ++i)
      h1[(size_t)(bg * 8 + i) * 256 + oc] = fmaxf(s[i] + bi, 0.f);
  }
}

// ---------------- fc2 ----------------
__global__ __launch_bounds__(256) void k_fc2_simple(const float* __restrict__ h1,
                                                    const float* __restrict__ w,
                                                    const float* __restrict__ bias,
                                                    float* __restrict__ out) {
  const int idx = blockIdx.x * 256 + threadIdx.x;
  if (idx >= 64 * 12) return;
  const int oc = idx % 12, b = idx / 12;
  const float* hb = h1 + (size_t)b * 256;
  const float* wr = w + (size_t)oc * 256;
  float s = bias[oc];
  for (int k = 0; k < 256; ++k) s += hb[k] * wr[k];
  out[b * 12 + oc] = s;
}

// ---------------- launch ----------------
extern "C" void kernel_launch(void* const* d_in, const int* in_sizes, int n_in,
                              void* d_out, int out_size, void* d_ws, size_t ws_size,
                              hipStream_t stream) {
  const float* img  = (const float*)d_in[0];
  const float* w1 = (const float*)d_in[1];  const float* b1 = (const float*)d_in[2];
  const float* w2 = (const float*)d_in[3];  const float* b2 = (const float*)d_in[4];
  const float* w3 = (const float*)d_in[5];  const float* b3 = (const float*)d_in[6];
  const float* w4 = (const float*)d_in[7];  const float* b4 = (const float*)d_in[8];
  const float* w5 = (const float*)d_in[9];  const float* b5 = (const float*)d_in[10];
  const float* fc1w = (const float*)d_in[11]; const float* fc1b = (const float*)d_in[12];
  const float* fc2w = (const float*)d_in[13]; const float* fc2b = (const float*)d_in[14];
  float* out = (float*)d_out;
  float* ws  = (float*)d_ws;

  float* hint = ws + OFF_HINT;
  float* hgrd = ws + OFF_HGRD;
  float* f    = ws + OFF_F;
  float* h1   = ws + OFF_H1;
  float* p5   = ws + OFF_P5;
  ushort_t* whi = (ushort_t*)(ws + OFF_WHI);
  ushort_t* wlo = (ushort_t*)(ws + OFF_WLO);
  ushort_t* ra  = (ushort_t*)(ws + OFF_RA);   // x0p / p1p / p2p ; a4p at +A4P_U16 (all NHWC)
  ushort_t* rb  = (ushort_t*)(ws + OFF_RB);   // a1 / a2 / a3p / a5 (all NHWC)

  hipMemsetAsync(hint, 0, (size_t)2 * 64 * 160 * sizeof(float), stream);
  hipMemsetAsync(ra, 0, (size_t)64 * 116 * 116 * 3 * 2, stream);   // x0p incl. zero ring

  k_wsplit_all<<<(int)((WP_U16 + 255) / 256), 256, 0, stream>>>(w1, w2, w3, w4, w5, whi, wlo);

  // fused hist + resize (single pass over the 205 MB image), x0p NHWC
  k_preproc<<<dim3(64, 56), 256, 0, stream>>>(img, hint, hgrd, ra);

  // conv1: [b][116][116][3] -> a1 [b][27][27][64] (RB)
  k_conv_mfma<3,116,116,11,11,4,27,27,27,27,0,64,64>
      <<<dim3(729, 1), 512, 0, stream>>>(ra, whi + W1_OFF, wlo + W1_OFF, b1, rb);
  // pool1 -> p1p [b][17][17][64] pad2 (RA)
  k_pool<64,27,13,17,2,false><<<(64*64*17*17 + 255)/256, 256, 0, stream>>>(rb, ra);
  // conv2: -> a2 [b][13][13][192] (RB)
  k_conv_mfma<64,17,17,5,5,1,13,13,13,13,0,192,64>
      <<<dim3(169, 3), 512, 0, stream>>>(ra, whi + W2_OFF, wlo + W2_OFF, b2, rb);
  // pool2 -> p2p [b][8][8][192] pad1 (RA)
  k_pool<192,13,6,8,1,false><<<(64*192*8*8 + 255)/256, 256, 0, stream>>>(rb, ra);
  // zero pad rings for conv3/conv4 padded outputs
  hipMemsetAsync(rb, 0, (size_t)64*384*8*8*2, stream);                      // a3p
  hipMemsetAsync(ra + A4P_U16, 0, (size_t)64*256*8*8*2, stream);            // a4p
  // conv3: p2p -> a3p [b][8][8][384] pad1 interior (RB)
  k_conv_mfma<192,8,8,3,3,1,6,6,8,8,1,384,32>
      <<<dim3(36, 12), 512, 0, stream>>>(ra, whi + W3_OFF, wlo + W3_OFF, b3, rb);
  // conv4: a3p -> a4p [b][8][8][256] pad1 interior (RA + A4P_U16)
  k_conv_mfma<384,8,8,3,3,1,6,6,8,8,1,256,32>
      <<<dim3(36, 8), 512, 0, stream>>>(rb, whi + W4_OFF, wlo + W4_OFF, b4, ra + A4P_U16);
  // conv5: a4p -> a5 [b][6][6][256] (RB)
  k_conv_mfma<256,8,8,3,3,1,6,6,6,6,0,256,32>
      <<<dim3(36, 8), 512, 0, stream>>>(ra + A4P_U16, whi + W5_OFF, wlo + W5_OFF, b5, rb);
  // pool5: NHWC a5 -> NCHW f32 p5 [b][256][2][2]
  k_pool<256,6,2,2,0,true><<<(64*256*2*2 + 255)/256, 256, 0, stream>>>(rb, p5);

  k_feat<<<64, 256, 0, stream>>>(p5, hint, hgrd, f);
  k_fc1<<<(256*8)/4, 256, 0, stream>>>(f, fc1w, fc1b, h1);
  k_fc2_simple<<<(64*12 + 255)/256, 256, 0, stream>>>(h1, fc2w, fc2b, out);
}